// Round 6
// baseline (346.023 us; speedup 1.0000x reference)
//
#include <hip/hip_runtime.h>
#include <math.h>

// Problem constants
#define B_    128
#define T_    2048
#define DIN   128
#define HID_  132
#define DOUT  64

// Tiling
#define TC    128            // time-steps per fused block
#define NCC   (T_ / TC)      // 16 chunks
#define AS    168            // act row stride (f16): 336B, 16B-aligned, conflict-benign

// sched_barrier mask: allow ALU|VALU|SALU|MFMA|VMEM to cross, block DS ops.
// Enforces LDS write->read order (same-wave DS ops execute in order in HW)
// without blocking global-load prefetch overlap.
#define DS_FENCE() __builtin_amdgcn_sched_barrier(0x7F)

typedef _Float16 half8   __attribute__((ext_vector_type(8)));
typedef _Float16 half4v  __attribute__((ext_vector_type(4)));
typedef float    float4v __attribute__((ext_vector_type(4)));

__device__ __forceinline__ float4v max4(float4v a, float4v b) {
    float4v r;
#pragma unroll
    for (int i = 0; i < 4; ++i) r[i] = fmaxf(a[i], b[i]);
    return r;
}

// ---------------------------------------------------------------------------
// Kernel 1: blocks [0,32): weight prep into fragment-ordered layout.
//           blocks [32, 32+2048): per-chunk column max of P (float4 loads).
// Swizzle (per layer, rows R, padded K = KP): element (k, n) lives at
//   ci=k/64, kr=k%64, kc=min(64,KP-64ci), g=kr/8, j=kr%8, h=g/4, q=g%4
//   off = ci*R*64 + (n/16)*16*kc + h*512 + q*128 + (n%16)*8 + j
// so lane (quad,l16) of a wave reads its half8 A-fragment for (kt, nt) at
//   SW + ci*R*64 + kt2*512 + nt*16*kc + quad*128 + l16*8      (contiguous 1KB
// per wave per fragment -> perfectly coalesced global_load_dwordx4).
// ---------------------------------------------------------------------------
__global__ __launch_bounds__(256) void prep_chunkmax_kernel(
    const float* __restrict__ P,
    const float* __restrict__ W1, const float* __restrict__ b1,
    const float* __restrict__ W2, const float* __restrict__ b2,
    const float* __restrict__ W3, const float* __restrict__ b3,
    const float* __restrict__ W4, const float* __restrict__ b4,
    float* __restrict__ cmax,
    _Float16* __restrict__ SW1, _Float16* __restrict__ SW2,
    _Float16* __restrict__ SW3, _Float16* __restrict__ SW4,
    float* __restrict__ bpad) {
    const int bid = blockIdx.x;
    const int tid = threadIdx.x;
    if (bid >= 32) {
        // ---- chunk max: (c4 0..31 covering d) x (sg 0..7 t-segments) ----
        __shared__ float4v smax1[256];
        const int cb = bid - 32;
        const int b = cb >> 4, c = cb & 15;
        const int c4 = tid & 31, sg = tid >> 5;
        const float* p = P + ((size_t)(b * T_ + c * TC + sg * 16)) * DIN + c4 * 4;
        float4v m = {-INFINITY, -INFINITY, -INFINITY, -INFINITY};
#pragma unroll
        for (int i = 0; i < 16; ++i)
            m = max4(m, *(const float4v*)(p + (size_t)i * DIN));
        smax1[sg * 32 + c4] = m;
        __syncthreads();
        if (tid < 32) {
            float4v r = smax1[tid];
#pragma unroll
            for (int s = 1; s < 8; ++s) r = max4(r, smax1[s * 32 + tid]);
            *(float4v*)(cmax + ((size_t)b * NCC + c) * DIN + tid * 4) = r;
        }
    } else {
        // ---- weight prep: 8 slice-blocks per layer, coalesced row reads ----
        const int l = bid >> 3, slice = bid & 7;
        const float *W, *bs; _Float16* dst; int K, N, KP, R, NB;
        if (l == 0)      { W = W1; bs = b1; dst = SW1; K = 128; N = 132; KP = 128; R = 144; NB = 132; }
        else if (l == 1) { W = W2; bs = b2; dst = SW2; K = 132; N = 132; KP = 160; R = 144; NB = 132; }
        else if (l == 2) { W = W3; bs = b3; dst = SW3; K = 132; N = 132; KP = 160; R = 144; NB = 132; }
        else             { W = W4; bs = b4; dst = SW4; K = 132; N = 64;  KP = 160; R = 64;  NB = 64;  }
        for (int k = slice; k < KP; k += 8) {
            const int ci = k >> 6, kr = k & 63;
            const int kc = (KP - (ci << 6) < 64) ? 32 : 64;
            const int g = kr >> 3, j = kr & 7, h = g >> 2, q = g & 3;
            for (int n = tid; n < R; n += 256) {
                float v = (k < K && n < N) ? W[(size_t)k * N + n] : 0.f;
                size_t off = (size_t)ci * R * 64 + (size_t)(n >> 4) * 16 * kc +
                             h * 512 + q * 128 + (n & 15) * 8 + j;
                dst[off] = (_Float16)v;
            }
        }
        if (slice == 0)
            for (int i = tid; i < 144; i += 256)
                bpad[l * 144 + i] = (i < NB) ? bs[i] : 0.f;
    }
}

// ---------------------------------------------------------------------------
// One MLP layer via 16x16x32 f16 MFMA, swapped operands (D = W x act -> D^T).
// 8 waves/block; wave w owns rows [16w,16w+16) -- ONE strip, so accumulators
// are 36 VGPRs (NT float4v) and 6 waves/SIMD fit under the 85-VGPR cap.
// All act accesses wave-private -> no barriers, DS_FENCE only.
// Weight fragments read directly from global (L2-resident, fragment-ordered,
// 1KB-coalesced per wave).
// ---------------------------------------------------------------------------
template <int NT, int KTOT, bool LAST>
__device__ __forceinline__ void mlp_layer(const _Float16* __restrict__ Wsw,
                                          const float* __restrict__ bp,
                                          _Float16* act,
                                          float* __restrict__ outg, int tid) {
    const int wave = tid >> 6, lane = tid & 63;
    const int quad = lane >> 4, l16 = lane & 15;
    constexpr int NKT = KTOT / 32;
    constexpr int R = NT * 16;
    float4v C0[NT];
#pragma unroll
    for (int nt = 0; nt < NT; ++nt) C0[nt] = (float4v)0.0f;

    const int r0 = 16 * wave + l16;
    const int lo = quad * 128 + l16 * 8;      // lane offset within a fragment

    // fragment address for (kt, nt); all terms compile-time after unroll
#define WPTR(kt_, nt_)                                                        \
    ((const half8*)(Wsw + ((kt_) >> 1) * (R * 64) + ((kt_) & 1) * 512 +       \
                    (nt_) * 16 * ((KTOT - ((kt_) >> 1) * 64 < 64) ? 32 : 64) + lo))

    DS_FENCE();   // prior phase's act ds_writes stay before our ds_reads
#pragma unroll
    for (int kt = 0; kt < NKT; ++kt) {
        const int ko = kt * 32 + quad * 8;
        half8 a0 = *(const half8*)(act + (size_t)r0 * AS + ko);
#pragma unroll
        for (int nt = 0; nt < NT; ++nt) {
            half8 w = *WPTR(kt, nt);          // global, L2-hot
            C0[nt] = __builtin_amdgcn_mfma_f32_16x16x32_f16(w, a0, C0[nt], 0, 0, 0);
        }
    }
#undef WPTR
    if (!LAST) DS_FENCE();   // our act ds_reads stay before in-place ds_writes
    const int m = 16 * wave + l16;
#pragma unroll
    for (int nt = 0; nt < NT; ++nt) {
        const int n0 = nt * 16 + quad * 4;
        float4v c = C0[nt];
        float4v bv = *(const float4v*)(bp + n0);
        if (LAST) {
            float4v o;
#pragma unroll
            for (int r = 0; r < 4; ++r)
                o[r] = 1.f / (1.f + __expf(-5.f * (c[r] + bv[r])));
            *(float4v*)(outg + (size_t)m * DOUT + n0) = o;
        } else {
            half4v hv;
#pragma unroll
            for (int r = 0; r < 4; ++r)
                hv[r] = (_Float16)fmaxf(c[r] + bv[r], 0.f);
            *(half4v*)(act + (size_t)m * AS + n0) = hv;
        }
    }
    // next layer's DS_FENCE orders these writes vs. its reads
}

// ---------------------------------------------------------------------------
// Fused kernel: reverse cummax (16 parallel 8-row segments, register-resident
// fold) -> 4 MFMA layers. 512 threads = 8 waves, 16 rows/wave.
// LDS = act (43008B) + smax (8192B) = 51200B -> 3 blocks/CU = 24 waves/CU
// (6 waves/SIMD, 2x the best measured TLP). __launch_bounds__(512,6) caps
// VGPR at 85 so 6 waves/SIMD actually materialize.
// ONE __syncthreads total (smax exchange); all other phases wave-private.
// ---------------------------------------------------------------------------
__global__ __launch_bounds__(512, 6) void fused_kernel(
    const float* __restrict__ P, const float* __restrict__ cmax,
    const _Float16* __restrict__ SW1, const _Float16* __restrict__ SW2,
    const _Float16* __restrict__ SW3, const _Float16* __restrict__ SW4,
    const float* __restrict__ bpad, float* __restrict__ Out) {
    __shared__ __align__(16) _Float16 act[TC * AS];      // 43008 B
    __shared__ __align__(16) float4v smax[512];          //  8192 B

    const int bid = blockIdx.x;
    const int b = bid / NCC, c = bid % NCC;
    const int tid = threadIdx.x;

    {   // zero K-pad cols [144,160) (read as A-operand by layers 2-4)
        // r = tid>>2: wave w zeroes rows [16w,16w+16) -- wave-private
        const int r = tid >> 2, part = tid & 3;
        uint2 z{0, 0};
        *(uint2*)(act + (size_t)r * AS + 144 + part * 4) = z;
    }
    {   // reverse cummax: 16 parallel 8-row t-segments, float4 columns.
        // sg = tid>>5: wave w owns segments {2w,2w+1} = rows [16w,16w+16).
        // Suffix maxes kept in REGISTERS across the barrier; act written once.
        const int c4 = tid & 31, sg = tid >> 5;
        const float* p = P + ((size_t)(b * T_ + c * TC + sg * 8)) * DIN + c4 * 4;
        float4v v[8];
#pragma unroll
        for (int i = 0; i < 8; ++i)          // all 8 HBM loads in flight
            v[i] = *(const float4v*)(p + (size_t)i * DIN);
        float4v run = {-INFINITY, -INFINITY, -INFINITY, -INFINITY};
#pragma unroll
        for (int i = 7; i >= 0; --i) {       // v[i] := suffix max within segment
            run = max4(run, v[i]);
            v[i] = run;
        }
        smax[sg * 32 + c4] = run;
        __syncthreads();     // the ONLY cross-wave exchange: smax visibility
        // tail = max over later chunks + later segments
        // fully unrolled: 15 clamped loads issue up-front, predicated fold
        float4v tail = {-INFINITY, -INFINITY, -INFINITY, -INFINITY};
#pragma unroll
        for (int j = 1; j < NCC; ++j) {
            const int jj = c + j;
            const int jc = (jj < NCC - 1) ? jj : NCC - 1;   // clamped (valid) addr
            float4v t = *(const float4v*)(cmax + ((size_t)b * NCC + jc) * DIN + c4 * 4);
            if (jj < NCC) tail = max4(tail, t);             // block-uniform predicate
        }
        for (int s = sg + 1; s < 16; ++s) tail = max4(tail, smax[s * 32 + c4]);
        // single store pass: act = cvt(max(suffix, tail))
#pragma unroll
        for (int i = 0; i < 8; ++i) {
            float4v f = max4(v[i], tail);
            half4v h;
#pragma unroll
            for (int j = 0; j < 4; ++j) h[j] = (_Float16)f[j];
            *(half4v*)(act + (size_t)(sg * 8 + i) * AS + c4 * 4) = h;
        }
        // mlp_layer's DS_FENCE orders these vs. fragment reads
    }

    float* outg = Out + (size_t)(b * T_ + c * TC) * DOUT;
    mlp_layer<9, 128, false>(SW1, bpad,       act, nullptr, tid);
    mlp_layer<9, 160, false>(SW2, bpad + 144, act, nullptr, tid);
    mlp_layer<9, 160, false>(SW3, bpad + 288, act, nullptr, tid);
    mlp_layer<4, 160, true >(SW4, bpad + 432, act, outg,    tid);
}

// ---------------------------------------------------------------------------
extern "C" void kernel_launch(void* const* d_in, const int* in_sizes, int n_in,
                              void* d_out, int out_size, void* d_ws, size_t ws_size,
                              hipStream_t stream) {
    const float* P  = (const float*)d_in[0];
    const float* W1 = (const float*)d_in[1];
    const float* b1 = (const float*)d_in[2];
    const float* W2 = (const float*)d_in[3];
    const float* b2 = (const float*)d_in[4];
    const float* W3 = (const float*)d_in[5];
    const float* b3 = (const float*)d_in[6];
    const float* W4 = (const float*)d_in[7];
    const float* b4 = (const float*)d_in[8];
    float* out = (float*)d_out;

    // ws layout
    char* ws = (char*)d_ws;
    float*    cmax = (float*)ws;                          // 1 MiB
    _Float16* SW1  = (_Float16*)(ws + (1 << 20));         // 144*128 f16 (frag-ordered)
    _Float16* SW2  = SW1 + 144 * 128;                     // 144*160
    _Float16* SW3  = SW2 + 144 * 160;                     // 144*160
    _Float16* SW4  = SW3 + 144 * 160;                     // 64*160
    float*    bpad = (float*)(SW4 + 64 * 160);            // 4*144 f32

    prep_chunkmax_kernel<<<B_ * NCC + 32, 256, 0, stream>>>(
        P, W1, b1, W2, b2, W3, b3, W4, b4, cmax, SW1, SW2, SW3, SW4, bpad);
    fused_kernel<<<B_ * NCC, 512, 0, stream>>>(P, cmax, SW1, SW2, SW3, SW4,
                                               bpad, out);
}

// Round 7
// 292.072 us; speedup vs baseline: 1.1847x; 1.1847x over previous
//
#include <hip/hip_runtime.h>
#include <math.h>

// Problem constants
#define B_    128
#define T_    2048
#define DIN   128
#define HID_  132
#define DOUT  64

// Tiling
#define TC    128            // time-steps per fused block
#define NCC   (T_ / TC)      // 16 chunks
#define AS    168            // act row stride (f16): 336B, 16B-aligned, conflict-benign

typedef _Float16 half8   __attribute__((ext_vector_type(8)));
typedef _Float16 half4v  __attribute__((ext_vector_type(4)));
typedef float    float4v __attribute__((ext_vector_type(4)));

// lgkm-only barrier: drains LDS ops and syncs the block WITHOUT waiting on
// in-flight global (vmcnt) loads -- weight prefetches survive the barrier.
// sched_barrier(0x7F) lets VALU/SALU/MFMA/VMEM cross but pins DS ops.
#define LBAR()                                                   \
    do {                                                         \
        asm volatile("s_waitcnt lgkmcnt(0)" ::: "memory");       \
        __builtin_amdgcn_s_barrier();                            \
        __builtin_amdgcn_sched_barrier(0x7F);                    \
    } while (0)

__device__ __forceinline__ float4v max4(float4v a, float4v b) {
    float4v r;
#pragma unroll
    for (int i = 0; i < 4; ++i) r[i] = fmaxf(a[i], b[i]);
    return r;
}

// ---------------------------------------------------------------------------
// Kernel 1: blocks [0,32): weight prep into fragment-ordered layout.
//           blocks [32, 32+2048): per-chunk column max of P (float4 loads).
// Swizzle (per layer, rows R, padded K = KP): element (k, n) lives at
//   ci=k/64, kr=k%64, kc=min(64,KP-64ci), g=kr/8, j=kr%8, h=g/4, q=g%4
//   off = ci*R*64 + (n/16)*16*kc + h*512 + q*128 + (n%16)*8 + j
// so lane (quad,l16) of a wave reads its half8 A-fragment for (kt, nt) at
//   SW + ci*R*64 + kt2*512 + nt*16*kc + quad*128 + l16*8      (contiguous 1KB
// per wave per fragment -> perfectly coalesced global_load_dwordx4).
// ---------------------------------------------------------------------------
__global__ __launch_bounds__(256) void prep_chunkmax_kernel(
    const float* __restrict__ P,
    const float* __restrict__ W1, const float* __restrict__ b1,
    const float* __restrict__ W2, const float* __restrict__ b2,
    const float* __restrict__ W3, const float* __restrict__ b3,
    const float* __restrict__ W4, const float* __restrict__ b4,
    float* __restrict__ cmax,
    _Float16* __restrict__ SW1, _Float16* __restrict__ SW2,
    _Float16* __restrict__ SW3, _Float16* __restrict__ SW4,
    float* __restrict__ bpad) {
    const int bid = blockIdx.x;
    const int tid = threadIdx.x;
    if (bid >= 32) {
        // ---- chunk max: (c4 0..31 covering d) x (sg 0..7 t-segments) ----
        __shared__ float4v smax1[256];
        const int cb = bid - 32;
        const int b = cb >> 4, c = cb & 15;
        const int c4 = tid & 31, sg = tid >> 5;
        const float* p = P + ((size_t)(b * T_ + c * TC + sg * 16)) * DIN + c4 * 4;
        float4v m = {-INFINITY, -INFINITY, -INFINITY, -INFINITY};
#pragma unroll
        for (int i = 0; i < 16; ++i)
            m = max4(m, *(const float4v*)(p + (size_t)i * DIN));
        smax1[sg * 32 + c4] = m;
        __syncthreads();
        if (tid < 32) {
            float4v r = smax1[tid];
#pragma unroll
            for (int s = 1; s < 8; ++s) r = max4(r, smax1[s * 32 + tid]);
            *(float4v*)(cmax + ((size_t)b * NCC + c) * DIN + tid * 4) = r;
        }
    } else {
        // ---- weight prep: 8 slice-blocks per layer, coalesced row reads ----
        const int l = bid >> 3, slice = bid & 7;
        const float *W, *bs; _Float16* dst; int K, N, KP, R, NB;
        if (l == 0)      { W = W1; bs = b1; dst = SW1; K = 128; N = 132; KP = 128; R = 144; NB = 132; }
        else if (l == 1) { W = W2; bs = b2; dst = SW2; K = 132; N = 132; KP = 160; R = 144; NB = 132; }
        else if (l == 2) { W = W3; bs = b3; dst = SW3; K = 132; N = 132; KP = 160; R = 144; NB = 132; }
        else             { W = W4; bs = b4; dst = SW4; K = 132; N = 64;  KP = 160; R = 64;  NB = 64;  }
        for (int k = slice; k < KP; k += 8) {
            const int ci = k >> 6, kr = k & 63;
            const int kc = (KP - (ci << 6) < 64) ? 32 : 64;
            const int g = kr >> 3, j = kr & 7, h = g >> 2, q = g & 3;
            for (int n = tid; n < R; n += 256) {
                float v = (k < K && n < N) ? W[(size_t)k * N + n] : 0.f;
                size_t off = (size_t)ci * R * 64 + (size_t)(n >> 4) * 16 * kc +
                             h * 512 + q * 128 + (n & 15) * 8 + j;
                dst[off] = (_Float16)v;
            }
        }
        if (slice == 0)
            for (int i = tid; i < 144; i += 256)
                bpad[l * 144 + i] = (i < NB) ? bs[i] : 0.f;
    }
}

// ---------------------------------------------------------------------------
// K-loop of one layer for one wave (2x2 wave grid: wt splits rows, wn splits
// n-tiles). Wave (wn,wt) computes C[j][s] for n-tiles NTBASE..NTBASE+NTW-1
// and strips s=0..3 of rows [64wt, 64wt+64). Each weight fragment is read by
// EXACTLY ONE wave (146KB/block total = minimum), and feeds 4 MFMAs.
// No barriers inside; caller places lgkm-only barriers.
// ---------------------------------------------------------------------------
template <int NT, int KTOT, int NTW, int NTBASE>
__device__ __forceinline__ void kloop(const _Float16* __restrict__ Wsw,
                                      const _Float16* __restrict__ act,
                                      float4v (&C)[5][4],
                                      int wt, int quad, int l16) {
    constexpr int NKT = KTOT / 32;
    constexpr int R = NT * 16;
#pragma unroll
    for (int j = 0; j < NTW; ++j)
#pragma unroll
        for (int s = 0; s < 4; ++s) C[j][s] = (float4v)0.0f;

    const _Float16* wb = Wsw + quad * 128 + l16 * 8;
    const _Float16* ab = act + (size_t)(64 * wt + l16) * AS + quad * 8;
#pragma unroll
    for (int kt = 0; kt < NKT; ++kt) {
        const int ci = kt >> 1, kt2 = kt & 1;              // compile-time after unroll
        const int kc = (KTOT - ci * 64 < 64) ? 32 : 64;
        half8 a[4];
#pragma unroll
        for (int s = 0; s < 4; ++s)
            a[s] = *(const half8*)(ab + (size_t)(16 * s) * AS + kt * 32);
#pragma unroll
        for (int j = 0; j < NTW; ++j) {
            const int nt = NTBASE + j;
            half8 w = *(const half8*)(wb + ci * (R * 64) + kt2 * 512 + nt * 16 * kc);
#pragma unroll
            for (int s = 0; s < 4; ++s)
                C[j][s] = __builtin_amdgcn_mfma_f32_16x16x32_f16(w, a[s], C[j][s], 0, 0, 0);
        }
    }
}

// ---------------------------------------------------------------------------
// Epilogue: bias + ReLU + f16 store to act (or sigmoid + f32 store to global).
// Wave writes rows [64wt,64wt+64) x cols [NTBASE*16, (NTBASE+NTW)*16) --
// disjoint across waves; caller barriers order it vs. reads.
// ---------------------------------------------------------------------------
template <int NTW, int NTBASE, bool LAST>
__device__ __forceinline__ void epi(float4v (&C)[5][4],
                                    const float* __restrict__ bp,
                                    _Float16* act, float* __restrict__ outg,
                                    int wt, int quad, int l16) {
#pragma unroll
    for (int j = 0; j < NTW; ++j) {
        const int n0 = (NTBASE + j) * 16 + quad * 4;
        float4v bv = *(const float4v*)(bp + n0);
#pragma unroll
        for (int s = 0; s < 4; ++s) {
            const int m = 64 * wt + 16 * s + l16;
            float4v c = C[j][s];
            if (LAST) {
                float4v o;
#pragma unroll
                for (int r = 0; r < 4; ++r)
                    o[r] = 1.f / (1.f + __expf(-5.f * (c[r] + bv[r])));
                *(float4v*)(outg + (size_t)m * DOUT + n0) = o;
            } else {
                half4v hv;
#pragma unroll
                for (int r = 0; r < 4; ++r)
                    hv[r] = (_Float16)fmaxf(c[r] + bv[r], 0.f);
                *(half4v*)(act + (size_t)m * AS + n0) = hv;
            }
        }
    }
}

// ---------------------------------------------------------------------------
// Fused kernel: reverse cummax (register-resident fold) -> 4 MFMA layers.
// 256 threads = 4 waves in a 2x2 grid: wt = wave&1 (row half), wn = wave>>1
// (n-tile half: layers 1-3 split 5/4, layer 4 split 2/2). Weight traffic =
// 146KB/block (each fragment read once). All barriers are lgkm-only (no
// vmcnt drain -> weight prefetch flows across them).
// LDS = act 43008 + smax 4096 = 47104B -> 3 blocks/CU (12 waves/CU).
// ---------------------------------------------------------------------------
__global__ __launch_bounds__(256, 3) void fused_kernel(
    const float* __restrict__ P, const float* __restrict__ cmax,
    const _Float16* __restrict__ SW1, const _Float16* __restrict__ SW2,
    const _Float16* __restrict__ SW3, const _Float16* __restrict__ SW4,
    const float* __restrict__ bpad, float* __restrict__ Out) {
    __shared__ __align__(16) _Float16 act[TC * AS];      // 43008 B
    __shared__ __align__(16) float4v smax[256];          //  4096 B

    const int bid = blockIdx.x;
    const int b = bid / NCC, c = bid % NCC;
    const int tid = threadIdx.x;
    const int wave = tid >> 6, lane = tid & 63;
    const int quad = lane >> 4, l16 = lane & 15;
    const int wt = wave & 1, wn = wave >> 1;

    float4v C[5][4];   // accumulators: up to 5 n-tiles x 4 strips

    {   // zero K-pad cols [144,160) (read as A-operand by layers 2-4)
        const int m = tid >> 1, s2 = tid & 1;
        uint4 z{0, 0, 0, 0};
        *(uint4*)(act + (size_t)m * AS + 144 + s2 * 8) = z;
    }
    {   // reverse cummax: 8 parallel 16-row t-segments, float4 columns.
        // sg = tid>>5: suffix maxes held in REGISTERS across the barrier;
        // act written exactly once (no LDS read-modify-write pass).
        const int c4 = tid & 31, sg = tid >> 5;
        const float* p = P + ((size_t)(b * T_ + c * TC + sg * 16)) * DIN + c4 * 4;
        float4v v[16];
#pragma unroll
        for (int i = 0; i < 16; ++i)         // all 16 HBM loads in flight
            v[i] = *(const float4v*)(p + (size_t)i * DIN);
        float4v run = {-INFINITY, -INFINITY, -INFINITY, -INFINITY};
#pragma unroll
        for (int i = 15; i >= 0; --i) {      // v[i] := suffix max within segment
            run = max4(run, v[i]);
            v[i] = run;
        }
        smax[sg * 32 + c4] = run;
        LBAR();                              // smax visibility (lgkm-only)
        // tail = max over later chunks + later segments
        float4v tail = {-INFINITY, -INFINITY, -INFINITY, -INFINITY};
#pragma unroll
        for (int j = 1; j < NCC; ++j) {
            const int jj = c + j;
            const int jc = (jj < NCC - 1) ? jj : NCC - 1;   // clamped (valid) addr
            float4v t = *(const float4v*)(cmax + ((size_t)b * NCC + jc) * DIN + c4 * 4);
            if (jj < NCC) tail = max4(tail, t);             // block-uniform predicate
        }
        for (int s = sg + 1; s < 8; ++s) tail = max4(tail, smax[s * 32 + c4]);
        // single store pass: act = cvt(max(suffix, tail))
#pragma unroll
        for (int i = 0; i < 16; ++i) {
            float4v f = max4(v[i], tail);
            half4v h;
#pragma unroll
            for (int j = 0; j < 4; ++j) h[j] = (_Float16)f[j];
            *(half4v*)(act + (size_t)(sg * 16 + i) * AS + c4 * 4) = h;
        }
    }
    LBAR();   // cummax act writes visible to all waves

    float* outg = Out + (size_t)(b * T_ + c * TC) * DOUT;

    // ---- layer 1 (K=128, NT=9: wn0 tiles 0-4, wn1 tiles 5-8) ----
    if (wn == 0) kloop<9, 128, 5, 0>(SW1, act, C, wt, quad, l16);
    else         kloop<9, 128, 4, 5>(SW1, act, C, wt, quad, l16);
    LBAR();   // all act reads done before in-place overwrite
    if (wn == 0) epi<5, 0, false>(C, bpad, act, nullptr, wt, quad, l16);
    else         epi<4, 5, false>(C, bpad, act, nullptr, wt, quad, l16);
    LBAR();   // layer-1 writes visible

    // ---- layer 2 (K=160) ----
    if (wn == 0) kloop<9, 160, 5, 0>(SW2, act, C, wt, quad, l16);
    else         kloop<9, 160, 4, 5>(SW2, act, C, wt, quad, l16);
    LBAR();
    if (wn == 0) epi<5, 0, false>(C, bpad + 144, act, nullptr, wt, quad, l16);
    else         epi<4, 5, false>(C, bpad + 144, act, nullptr, wt, quad, l16);
    LBAR();

    // ---- layer 3 (K=160) ----
    if (wn == 0) kloop<9, 160, 5, 0>(SW3, act, C, wt, quad, l16);
    else         kloop<9, 160, 4, 5>(SW3, act, C, wt, quad, l16);
    LBAR();
    if (wn == 0) epi<5, 0, false>(C, bpad + 288, act, nullptr, wt, quad, l16);
    else         epi<4, 5, false>(C, bpad + 288, act, nullptr, wt, quad, l16);
    LBAR();

    // ---- layer 4 (K=160, NT=4: 2 tiles each; writes global, no barrier) ----
    if (wn == 0) kloop<4, 160, 2, 0>(SW4, act, C, wt, quad, l16);
    else         kloop<4, 160, 2, 2>(SW4, act, C, wt, quad, l16);
    if (wn == 0) epi<2, 0, true>(C, bpad + 432, act, outg, wt, quad, l16);
    else         epi<2, 2, true>(C, bpad + 432, act, outg, wt, quad, l16);
}

// ---------------------------------------------------------------------------
extern "C" void kernel_launch(void* const* d_in, const int* in_sizes, int n_in,
                              void* d_out, int out_size, void* d_ws, size_t ws_size,
                              hipStream_t stream) {
    const float* P  = (const float*)d_in[0];
    const float* W1 = (const float*)d_in[1];
    const float* b1 = (const float*)d_in[2];
    const float* W2 = (const float*)d_in[3];
    const float* b2 = (const float*)d_in[4];
    const float* W3 = (const float*)d_in[5];
    const float* b3 = (const float*)d_in[6];
    const float* W4 = (const float*)d_in[7];
    const float* b4 = (const float*)d_in[8];
    float* out = (float*)d_out;

    // ws layout
    char* ws = (char*)d_ws;
    float*    cmax = (float*)ws;                          // 1 MiB
    _Float16* SW1  = (_Float16*)(ws + (1 << 20));         // 144*128 f16 (frag-ordered)
    _Float16* SW2  = SW1 + 144 * 128;                     // 144*160
    _Float16* SW3  = SW2 + 144 * 160;                     // 144*160
    _Float16* SW4  = SW3 + 144 * 160;                     // 64*160
    float*    bpad = (float*)(SW4 + 64 * 160);            // 4*144 f32

    prep_chunkmax_kernel<<<B_ * NCC + 32, 256, 0, stream>>>(
        P, W1, b1, W2, b2, W3, b3, W4, b4, cmax, SW1, SW2, SW3, SW4, bpad);
    fused_kernel<<<B_ * NCC, 256, 0, stream>>>(P, cmax, SW1, SW2, SW3, SW4,
                                               bpad, out);
}